// Round 14
// baseline (747.492 us; speedup 1.0000x reference)
//
#include <hip/hip_runtime.h>

namespace {

constexpr int Bn = 8192;
constexpr int Tn = 365;
constexpr int Hn = 34;
constexpr int WB = 16;      // batches per GROUP
constexpr int NG = 2;       // independent groups per wave (fills latency stalls)
constexpr int KP = 104;     // a_lds row stride in shorts (208 B, 16B-aligned)
constexpr float L2E = 1.44269504088896340736f;

typedef __attribute__((ext_vector_type(8))) short bf16x8;   // 8 bf16 = 4 VGPR
typedef __attribute__((ext_vector_type(4))) float f32x4;    // 16x16 MFMA acc

__device__ __forceinline__ float fexp2(float v) { return __builtin_amdgcn_exp2f(v); }
__device__ __forceinline__ float frcp(float v)  { return __builtin_amdgcn_rcpf(v); }

__device__ __forceinline__ unsigned short f2bf(float f) {   // RNE f32->bf16
    union { float f; unsigned u; } v; v.f = f;
    unsigned r = v.u + 0x7fffu + ((v.u >> 16) & 1u);
    return (unsigned short)(r >> 16);
}
__device__ __forceinline__ float bf2f(unsigned short s) {
    union { unsigned u; float f; } v; v.u = ((unsigned)s) << 16; return v.f;
}
// pack h into hi/lo bf16 pair (low short = h_h at even k, high short = h_l)
__device__ __forceinline__ unsigned packh(float h) {
    unsigned short hh = f2bf(h);
    unsigned short hl = f2bf(h - bf2f(hh));
    return (unsigned)hh | ((unsigned)hl << 16);
}

// Intra-wave LDS handoff fence (REQUIRED: packh stores and B-frag loads are
// TBAA-distinct; without it the write->read handoff races — R12 replay flake).
__device__ __forceinline__ void lds_fence() {
    __builtin_amdgcn_sched_barrier(0);
    asm volatile("s_waitcnt lgkmcnt(0)" ::: "memory");
    __builtin_amdgcn_sched_barrier(0);
}

// K-layout (79 used of 96; pads stay zero).  Weight rows PRE-SCALED by
// s(gate): -log2e (i,f,o) / +2*log2e (g):
//   sigmoid = rcp(1+exp2(acc)),  tanh = fma(-2, rcp(1+exp2(acc)), 1).
//   k=2j: h_h[j]<->bf16(s*w_hh) ; k=2j+1: h_l[j]<->same
//   k68-70: x_h<->bf16(s*Wc) ; k71-73: x_l<->same ; k74-76: x_h<->residual
//   k77: 1.0<->bias_h ; k78: 1.0<->bias_l
// D mapping: lane (qg=lane>>4, b=lane&15), reg p of tile tau = gate p of cell
// 4*tau+qg, batch b.  Cell update fully lane-local: zero barriers.

__global__ __launch_bounds__(64) void lstm_kernel(
    const float* __restrict__ x,      // [B,T,3]
    const float* __restrict__ fc0_w,  // [34,3]
    const float* __restrict__ fc0_b,  // [34]
    const float* __restrict__ w_ih,   // [136,34]
    const float* __restrict__ w_hh,   // [136,34]
    const float* __restrict__ b_ih,   // [136]
    const float* __restrict__ b_hh,   // [136]
    float* __restrict__ out)          // [B,T,34]
{
    __shared__ __align__(16) unsigned short a_lds[NG][2][WB][KP]; // [group][dbuf]

    const int lane = threadIdx.x;   // 0..63 (one wave per block)
    const int b    = lane & 15;     // batch col (B-frag) / A-frag row index
    const int qg   = lane >> 4;     // k-group for frags; q for D rows

    // ---- one-time: weight A-fragments Wt[9][3] — SHARED by both groups ----
    bf16x8 Wt[9][3];
    #pragma unroll
    for (int tau = 0; tau < 9; ++tau) {
        const int rhat = 16 * tau + b;
        const int cell = rhat >> 2, g = rhat & 3;
        const bool valid = (cell < Hn);
        const int r = g * Hn + (valid ? cell : 0);
        const float s = (g == 2) ? (2.f * L2E) : (-L2E);
        float wcv[3] = {0.f, 0.f, 0.f};
        float bia = 0.f;
        if (valid) {
            float ab = 0.f;
            for (int m = 0; m < Hn; ++m) {
                const float wi = w_ih[r * Hn + m];
                wcv[0] += wi * fc0_w[m * 3 + 0];
                wcv[1] += wi * fc0_w[m * 3 + 1];
                wcv[2] += wi * fc0_w[m * 3 + 2];
                ab     += wi * fc0_b[m];
            }
            wcv[0] *= s; wcv[1] *= s; wcv[2] *= s;
            bia = s * (ab + b_ih[r] + b_hh[r]);
        }
        #pragma unroll
        for (int ks = 0; ks < 3; ++ks) {
            bf16x8 f;
            #pragma unroll
            for (int e = 0; e < 8; ++e) {
                const int k = ks * 32 + qg * 8 + e;
                float val = 0.f;
                if (valid) {
                    if (k < 68)       val = s * w_hh[r * Hn + (k >> 1)];
                    else if (k < 71)  val = wcv[k - 68];
                    else if (k < 74)  val = wcv[k - 71];
                    else if (k < 77)  { const float w = wcv[k - 74]; val = w - bf2f(f2bf(w)); }
                    else if (k == 77) val = bia;
                    else if (k == 78) val = bia - bf2f(f2bf(bia));
                }
                f[e] = (short)f2bf(val);
            }
            Wt[tau][ks] = f;
        }
    }

    // ---- init LDS; fence; bias + x(0) for both groups ----
    for (int i = lane; i < NG * 2 * WB * KP; i += 64) ((unsigned short*)a_lds)[i] = 0;
    lds_fence();

    if (lane < 32) {
        a_lds[0][lane >> 4][b][77] = (unsigned short)0x3F80;
        a_lds[0][lane >> 4][b][78] = (unsigned short)0x3F80;
        a_lds[1][lane >> 4][b][77] = (unsigned short)0x3F80;
        a_lds[1][lane >> 4][b][78] = (unsigned short)0x3F80;
    }
    const int bx = lane / 3, ix = lane - 3 * (lane / 3);   // x staging (lane<48)
    const float* xwA = x + ((long long)blockIdx.x * (NG * WB)) * (Tn * 3);
    const float* xwB = xwA + (long long)WB * (Tn * 3);
    if (lane < 48) {
        float xr = xwA[bx * (Tn * 3) + ix];
        unsigned short xh = f2bf(xr);
        a_lds[0][0][bx][68 + ix] = xh;
        a_lds[0][0][bx][71 + ix] = f2bf(xr - bf2f(xh));
        a_lds[0][0][bx][74 + ix] = xh;
        xr = xwB[bx * (Tn * 3) + ix];
        xh = f2bf(xr);
        a_lds[1][0][bx][68 + ix] = xh;
        a_lds[1][0][bx][71 + ix] = f2bf(xr - bf2f(xh));
        a_lds[1][0][bx][74 + ix] = xh;
    }

    const long long TH = (long long)Tn * Hn;
    float* poutA = out + ((long long)blockIdx.x * (NG * WB) + b) * TH + qg;
    float* poutB = poutA + (long long)WB * TH;

    float cstA[9] = {0.f, 0.f, 0.f, 0.f, 0.f, 0.f, 0.f, 0.f, 0.f};
    float cstB[9] = {0.f, 0.f, 0.f, 0.f, 0.f, 0.f, 0.f, 0.f, 0.f};

    for (int t = 0; t < Tn; ++t) {
        const int cur = t & 1, nxt = cur ^ 1;

        // fence: prior step's packh/x LDS writes (both groups) -> this step's reads
        lds_fence();

        // ---- B-fragments for both groups ----
        bf16x8 avA[3], avB[3];
        #pragma unroll
        for (int ks = 0; ks < 3; ++ks) {
            avA[ks] = *(const bf16x8*)(&a_lds[0][cur][b][ks * 32 + qg * 8]);
            avB[ks] = *(const bf16x8*)(&a_lds[1][cur][b][ks * 32 + qg * 8]);
        }

        // prefetch next step's x (both groups)
        float xrA = 0.f, xrB = 0.f;
        if (lane < 48 && t + 1 < Tn) {
            xrA = xwA[bx * (Tn * 3) + (t + 1) * 3 + ix];
            xrB = xwB[bx * (Tn * 3) + (t + 1) * 3 + ix];
        }

        // ---- phase 1: all 54 MFMAs (18 independent 3-chains) ----
        f32x4 aA[9], aB[9];
        #pragma unroll
        for (int tau = 0; tau < 9; ++tau) {
            aA[tau] = f32x4{0.f, 0.f, 0.f, 0.f};
            aB[tau] = f32x4{0.f, 0.f, 0.f, 0.f};
            #pragma unroll
            for (int ks = 0; ks < 3; ++ks) {
                aA[tau] = __builtin_amdgcn_mfma_f32_16x16x32_bf16(Wt[tau][ks], avA[ks], aA[tau], 0, 0, 0);
                aB[tau] = __builtin_amdgcn_mfma_f32_16x16x32_bf16(Wt[tau][ks], avB[ks], aB[tau], 0, 0, 0);
            }
        }

        // ---- phase 2: exp2 over all 72 gate values ----
        #pragma unroll
        for (int tau = 0; tau < 9; ++tau)
            #pragma unroll
            for (int p = 0; p < 4; ++p) {
                aA[tau][p] = fexp2(aA[tau][p]);
                aB[tau][p] = fexp2(aB[tau][p]);
            }

        // ---- phase 3: rcp: u = rcp(1+e) ----
        #pragma unroll
        for (int tau = 0; tau < 9; ++tau)
            #pragma unroll
            for (int p = 0; p < 4; ++p) {
                aA[tau][p] = frcp(1.f + aA[tau][p]);
                aB[tau][p] = frcp(1.f + aB[tau][p]);
            }

        // ---- phase 4: c/h updates, packh + scattered fire-and-forget stores ----
        #pragma unroll
        for (int tau = 0; tau < 9; ++tau) {
            {
                const float gi = aA[tau][0], gf = aA[tau][1];
                const float gg = fmaf(-2.f, aA[tau][2], 1.f);
                const float go = aA[tau][3];
                cstA[tau] = gf * cstA[tau] + gi * gg;
                const float e2 = fexp2(cstA[tau] * (2.f * L2E));
                const float h  = go * fmaf(-2.f, frcp(1.f + e2), 1.f);
                if (tau < 8 || qg < 2) {
                    ((unsigned*)&a_lds[0][nxt][b][0])[4 * tau + qg] = packh(h);
                    poutA[(long long)t * Hn + 4 * tau] = h;
                }
            }
            {
                const float gi = aB[tau][0], gf = aB[tau][1];
                const float gg = fmaf(-2.f, aB[tau][2], 1.f);
                const float go = aB[tau][3];
                cstB[tau] = gf * cstB[tau] + gi * gg;
                const float e2 = fexp2(cstB[tau] * (2.f * L2E));
                const float h  = go * fmaf(-2.f, frcp(1.f + e2), 1.f);
                if (tau < 8 || qg < 2) {
                    ((unsigned*)&a_lds[1][nxt][b][0])[4 * tau + qg] = packh(h);
                    poutB[(long long)t * Hn + 4 * tau] = h;
                }
            }
        }

        // ---- stage x(t+1) for both groups ----
        if (lane < 48) {
            unsigned short xh = f2bf(xrA);
            a_lds[0][nxt][bx][68 + ix] = xh;
            a_lds[0][nxt][bx][71 + ix] = f2bf(xrA - bf2f(xh));
            a_lds[0][nxt][bx][74 + ix] = xh;
            xh = f2bf(xrB);
            a_lds[1][nxt][bx][68 + ix] = xh;
            a_lds[1][nxt][bx][71 + ix] = f2bf(xrB - bf2f(xh));
            a_lds[1][nxt][bx][74 + ix] = xh;
        }
    }
}

} // namespace

extern "C" void kernel_launch(void* const* d_in, const int* in_sizes, int n_in,
                              void* d_out, int out_size, void* d_ws, size_t ws_size,
                              hipStream_t stream) {
    const float* x     = (const float*)d_in[0];
    const float* fc0_w = (const float*)d_in[1];
    const float* fc0_b = (const float*)d_in[2];
    const float* w_ih  = (const float*)d_in[3];
    const float* w_hh  = (const float*)d_in[4];
    const float* b_ih  = (const float*)d_in[5];
    const float* b_hh  = (const float*)d_in[6];
    float* out = (float*)d_out;

    lstm_kernel<<<Bn / (NG * WB), 64, 0, stream>>>(x, fc0_w, fc0_b, w_ih, w_hh, b_ih, b_hh, out);
}

// Round 15
// 409.371 us; speedup vs baseline: 1.8260x; 1.8260x over previous
//
#include <hip/hip_runtime.h>

namespace {

constexpr int Bn = 8192;
constexpr int Tn = 365;
constexpr int Hn = 34;
constexpr int GB = 16;      // batches per block -> grid 512, 2 blocks/CU
constexpr int KP = 104;     // a_lds row stride in shorts (208 B = 52 words; 2-way banks)
constexpr int GS = 44;      // g_lds row stride in floats

constexpr float L2E = 1.44269504088896340736f;

typedef __attribute__((ext_vector_type(8))) short bf16x8;   // 8 bf16 = 4 VGPR
typedef __attribute__((ext_vector_type(4))) float f32x4;    // 16x16 MFMA acc

__device__ __forceinline__ float fexp2(float v) { return __builtin_amdgcn_exp2f(v); }
__device__ __forceinline__ float frcp(float v)  { return __builtin_amdgcn_rcpf(v); }

__device__ __forceinline__ unsigned short f2bf(float f) {   // RNE f32->bf16
    union { float f; unsigned u; } v; v.f = f;
    unsigned r = v.u + 0x7fffu + ((v.u >> 16) & 1u);
    return (unsigned short)(r >> 16);
}
__device__ __forceinline__ float bf2f(unsigned short s) {
    union { unsigned u; float f; } v; v.u = ((unsigned)s) << 16; return v.f;
}
__device__ __forceinline__ unsigned packh(float h) {
    unsigned short hh = f2bf(h);
    unsigned short hl = f2bf(h - bf2f(hh));
    return (unsigned)hh | ((unsigned)hl << 16);
}

// intra-wave LDS write->read handoff fence (TBAA-distinct accesses; R12 lesson)
__device__ __forceinline__ void lds_fence() {
    __builtin_amdgcn_sched_barrier(0);
    asm volatile("s_waitcnt lgkmcnt(0)" ::: "memory");
    __builtin_amdgcn_sched_barrier(0);
}
// cross-wave LDS barrier WITHOUT the vmcnt drain __syncthreads would add:
// LDS writes drained (lgkmcnt), then raw s_barrier. Global stores stay in
// flight across steps — fire-and-forget.
__device__ __forceinline__ void block_sync_lds() {
    __builtin_amdgcn_sched_barrier(0);
    asm volatile("s_waitcnt lgkmcnt(0)" ::: "memory");
    __builtin_amdgcn_s_barrier();
    __builtin_amdgcn_sched_barrier(0);
}

// K-layout (77 used of 96; pads stay zero). Weight rows PRE-SCALED by s(gate):
// -log2e (i,f,o) / +2*log2e (g)  =>  sigmoid = rcp(1+exp2(acc)),
// tanh = fma(-2, rcp(1+exp2(acc)), 1)  — no argument multiply at runtime.
//   k=2j: h_h[j]<->bf16(s*w_hh[r][j]) ; k=2j+1: h_l[j]<->same
//   k68-70: x_h<->bf16(s*Wc) ; k71-73: x_l<->same ; k74-76: x_h<->residual
// N-packing: rhat = 4*jl + g (jl = wave-local cell, g = gate i,f,g,o)

__global__ __launch_bounds__(256) void lstm_kernel(
    const float* __restrict__ x,      // [B,T,3]
    const float* __restrict__ fc0_w,  // [34,3]
    const float* __restrict__ fc0_b,  // [34]
    const float* __restrict__ w_ih,   // [136,34]
    const float* __restrict__ w_hh,   // [136,34]
    const float* __restrict__ b_ih,   // [136]
    const float* __restrict__ b_hh,   // [136]
    float* __restrict__ out)          // [B,T,34]
{
    __shared__ __align__(16) unsigned short a_lds[2][GB][KP]; // A operand, double-buffered
    __shared__ __align__(16) float g_lds[4][GB][GS];          // per-WAVE gate slice

    const int tid  = threadIdx.x;
    const int lane = tid & 63;
    const int wv   = tid >> 6;      // wave id
    const int c    = lane & 15;     // MFMA col (rhat within tile) / A-row (batch)
    const int kg   = lane >> 4;     // k-group / C-row group

    // cell partition across waves: {9,9,8,8}
    const int nc   = (wv < 2) ? 9 : 8;
    const int base = (wv < 2) ? 9 * wv : 18 + 8 * (wv - 2);

    // ---- one-time: B-fragments (3 N-tiles x 3 K-chunks), prescaled ----
    bf16x8 Bt[3][3];
    #pragma unroll
    for (int tau = 0; tau < 3; ++tau) {
        const int rhat = 16 * tau + c;
        const int jl = rhat >> 2, g = rhat & 3;
        const int r = (rhat < 4 * nc) ? g * Hn + (base + jl) : -1;
        const float s = (g == 2) ? (2.f * L2E) : (-L2E);
        float wcv[3] = {0.f, 0.f, 0.f};
        float bia = 0.f;
        if (r >= 0) {
            float ab = 0.f;
            for (int m = 0; m < Hn; ++m) {
                const float wi = w_ih[r * Hn + m];
                wcv[0] += wi * fc0_w[m * 3 + 0];
                wcv[1] += wi * fc0_w[m * 3 + 1];
                wcv[2] += wi * fc0_w[m * 3 + 2];
                ab     += wi * fc0_b[m];
            }
            wcv[0] *= s; wcv[1] *= s; wcv[2] *= s;
            bia = s * (ab + b_ih[r] + b_hh[r]);
        }
        #pragma unroll
        for (int ks = 0; ks < 3; ++ks) {
            bf16x8 f;
            #pragma unroll
            for (int e = 0; e < 8; ++e) {
                const int k = ks * 32 + kg * 8 + e;
                float val = 0.f;
                if (r >= 0) {
                    if (k < 68)       val = s * w_hh[r * Hn + (k >> 1)];
                    else if (k < 71)  val = wcv[k - 68];
                    else if (k < 74)  val = wcv[k - 71];
                    else if (k < 77)  { const float w = wcv[k - 74]; val = w - bf2f(f2bf(w)); }
                    else if (k == 77) val = bia;                      // bias_h (x1.0 slot)
                    else if (k == 78) val = bia - bf2f(f2bf(bia));    // bias_l
                }
                f[e] = (short)f2bf(val);
            }
            Bt[tau][ks] = f;
        }
    }

    // per-lane nonlinearity constants: gate = c&3 (tau-independent); scale folded
    const bool isg2 = ((c & 3) == 2);
    const float ku = isg2 ? -2.f : 1.f;    // out = ku*u + kc, u = rcp(1+exp2(acc))
    const float kc = isg2 ?  1.f : 0.f;

    // update-phase mapping: batch ub = c, cells {kg, 4+kg, 8 if kg==0 && nc==9}
    const int ub = c;
    const bool has2 = (nc == 9) && (kg == 0);
    float c0 = 0.f, c1 = 0.f, c2 = 0.f;
    float h0 = 0.f, h1 = 0.f, h2 = 0.f;

    // x staging: wave w stages batches 4w..4w+3 (12 lanes x 1 feature)
    const bool xact = (lane < 12);
    const int bx = 4 * wv + lane / 3;
    const int ix = lane - 3 * (lane / 3);

    // ---- zero both A buffers; barrier; bias-1.0 slots + x(0); barrier ----
    for (int i = tid; i < 2 * GB * KP; i += 256) ((unsigned short*)a_lds)[i] = 0;
    block_sync_lds();

    const long long bg = (long long)blockIdx.x * GB;
    const float* xblk = x + bg * (long long)(Tn * 3);
    float* oblk = out + bg * (long long)(Tn * Hn);
    const long long TH = (long long)Tn * Hn;

    if (tid < 32) {   // constant-1.0 slots (bias path), both buffers
        a_lds[tid >> 4][tid & 15][77] = (unsigned short)0x3F80;
        a_lds[tid >> 4][tid & 15][78] = (unsigned short)0x3F80;
    }
    if (xact) {
        const float xr = xblk[bx * (Tn * 3) + ix];
        const unsigned short xh = f2bf(xr);
        a_lds[0][bx][68 + ix] = xh;
        a_lds[0][bx][71 + ix] = f2bf(xr - bf2f(xh));
        a_lds[0][bx][74 + ix] = xh;
    }
    block_sync_lds();

    for (int t = 0; t < Tn; ++t) {
        const int cur = t & 1, nxt = cur ^ 1;

        // ---- top of step: issue global ops (retire under compute; never drained) ----
        if (t) {   // store h(t-1) from registers
            const long long tb = (long long)ub * TH + (long long)(t - 1) * Hn + base;
            oblk[tb + kg]     = h0;
            oblk[tb + 4 + kg] = h1;
            if (has2) oblk[tb + 8] = h2;
        }
        float xr = 0.f;
        if (xact && t + 1 < Tn)
            xr = xblk[bx * (Tn * 3) + (t + 1) * 3 + ix];

        // ---- A fragments (row = batch = c) ----
        bf16x8 av[3];
        #pragma unroll
        for (int ks = 0; ks < 3; ++ks)
            av[ks] = *(const bf16x8*)(&a_lds[cur][c][ks * 32 + kg * 8]);

        // ---- MFMA: this wave's cells x all 16 batches ----
        f32x4 acc[3];
        #pragma unroll
        for (int tau = 0; tau < 3; ++tau) {
            acc[tau] = f32x4{0.f, 0.f, 0.f, 0.f};
            #pragma unroll
            for (int ks = 0; ks < 3; ++ks)
                acc[tau] = __builtin_amdgcn_mfma_f32_16x16x32_bf16(av[ks], Bt[tau][ks], acc[tau], 0, 0, 0);
        }

        // ---- branchless nonlinearity (scale pre-folded) + write to wave-private g_lds ----
        #pragma unroll
        for (int tau = 0; tau < 3; ++tau) {
            #pragma unroll
            for (int p = 0; p < 4; ++p) {
                const float e2 = fexp2(acc[tau][p]);
                const float u  = frcp(1.f + e2);
                const float gv = fmaf(ku, u, kc);
                if (16 * tau + c < 4 * nc)
                    g_lds[wv][4 * kg + p][16 * tau + c] = gv;
            }
        }

        lds_fence();   // in-wave: gate writes -> gate reads

        // ---- update: lane = (batch ub, cells kg / 4+kg / [8]) ----
        {
            const f32x4 gv = *(const f32x4*)&g_lds[wv][ub][4 * kg];
            c0 = gv[1] * c0 + gv[0] * gv[2];
            h0 = gv[3] * fmaf(-2.f, frcp(1.f + fexp2(c0 * (2.f * L2E))), 1.f);
            ((unsigned*)&a_lds[nxt][ub][0])[base + kg] = packh(h0);
        }
        {
            const f32x4 gv = *(const f32x4*)&g_lds[wv][ub][4 * (4 + kg)];
            c1 = gv[1] * c1 + gv[0] * gv[2];
            h1 = gv[3] * fmaf(-2.f, frcp(1.f + fexp2(c1 * (2.f * L2E))), 1.f);
            ((unsigned*)&a_lds[nxt][ub][0])[base + 4 + kg] = packh(h1);
        }
        if (has2) {
            const f32x4 gv = *(const f32x4*)&g_lds[wv][ub][4 * 8];
            c2 = gv[1] * c2 + gv[0] * gv[2];
            h2 = gv[3] * fmaf(-2.f, frcp(1.f + fexp2(c2 * (2.f * L2E))), 1.f);
            ((unsigned*)&a_lds[nxt][ub][0])[base + 8] = packh(h2);
        }

        // ---- stage x(t+1) into next A buffer ----
        if (xact) {
            const unsigned short xh = f2bf(xr);
            a_lds[nxt][bx][68 + ix] = xh;
            a_lds[nxt][bx][71 + ix] = f2bf(xr - bf2f(xh));
            a_lds[nxt][bx][74 + ix] = xh;
        }

        block_sync_lds();   // the ONE barrier: h(t) visible to all waves (no vmem drain)
    }

    // final store: h(Tn-1)
    {
        const long long tb = (long long)ub * TH + (long long)(Tn - 1) * Hn + base;
        oblk[tb + kg]     = h0;
        oblk[tb + 4 + kg] = h1;
        if (has2) oblk[tb + 8] = h2;
    }
}

} // namespace

extern "C" void kernel_launch(void* const* d_in, const int* in_sizes, int n_in,
                              void* d_out, int out_size, void* d_ws, size_t ws_size,
                              hipStream_t stream) {
    const float* x     = (const float*)d_in[0];
    const float* fc0_w = (const float*)d_in[1];
    const float* fc0_b = (const float*)d_in[2];
    const float* w_ih  = (const float*)d_in[3];
    const float* w_hh  = (const float*)d_in[4];
    const float* b_ih  = (const float*)d_in[5];
    const float* b_hh  = (const float*)d_in[6];
    float* out = (float*)d_out;

    lstm_kernel<<<Bn / GB, 256, 0, stream>>>(x, fc0_w, fc0_b, w_ih, w_hh, b_ih, b_hh, out);
}

// Round 16
// 370.592 us; speedup vs baseline: 2.0170x; 1.1046x over previous
//
#include <hip/hip_runtime.h>

namespace {

constexpr int Bn = 8192;
constexpr int Tn = 365;
constexpr int Hn = 34;
constexpr int GB = 16;      // batches per block -> grid 512, 2 blocks/CU
constexpr int KP = 104;     // a_lds row stride in shorts (208 B = 52 words; 2-way banks)

constexpr float L2E = 1.44269504088896340736f;

typedef __attribute__((ext_vector_type(8))) short bf16x8;   // 8 bf16 = 4 VGPR
typedef __attribute__((ext_vector_type(4))) float f32x4;    // 16x16 MFMA acc

__device__ __forceinline__ float fexp2(float v) { return __builtin_amdgcn_exp2f(v); }
__device__ __forceinline__ float frcp(float v)  { return __builtin_amdgcn_rcpf(v); }

__device__ __forceinline__ unsigned short f2bf(float f) {   // RNE f32->bf16
    union { float f; unsigned u; } v; v.f = f;
    unsigned r = v.u + 0x7fffu + ((v.u >> 16) & 1u);
    return (unsigned short)(r >> 16);
}
__device__ __forceinline__ float bf2f(unsigned short s) {
    union { unsigned u; float f; } v; v.u = ((unsigned)s) << 16; return v.f;
}
__device__ __forceinline__ unsigned packh(float h) {
    unsigned short hh = f2bf(h);
    unsigned short hl = f2bf(h - bf2f(hh));
    return (unsigned)hh | ((unsigned)hl << 16);
}

// cross-wave LDS barrier WITHOUT the vmcnt drain __syncthreads would add:
// LDS writes drained (lgkmcnt), then raw s_barrier. Global stores/loads stay
// in flight across steps — fire-and-forget.
__device__ __forceinline__ void block_sync_lds() {
    __builtin_amdgcn_sched_barrier(0);
    asm volatile("s_waitcnt lgkmcnt(0)" ::: "memory");
    __builtin_amdgcn_s_barrier();
    __builtin_amdgcn_sched_barrier(0);
}

// K-layout (79 used of 96; pads stay zero). Weight rows PRE-SCALED by s(gate):
// -log2e (i,f,o) / +2*log2e (g)  =>  sigmoid = rcp(1+exp2(acc)),
// tanh = fma(-2, rcp(1+exp2(acc)), 1).
//   k=2j: h_h[j]<->bf16(s*w_hh[r][j]) ; k=2j+1: h_l[j]<->same
//   k68-70: x_h<->bf16(s*Wc) ; k71-73: x_l<->same ; k74-76: x_h<->residual
//   k77: 1.0<->bias_h ; k78: 1.0<->bias_l
//
// SWAPPED-OPERAND MFMA (R16): D = W'(rhat x k) * data(k x batch).
// C/D layout (m89/m91): col = lane&15 = BATCH, row = 4*(lane>>4) + reg = rhat.
// With rhat = 4*jl + gate, lane (kg, b) tile tau holds gates i,f,g,o (regs 0-3)
// of cell jl = 4*tau + kg, batch b  ->  cell update is LANE-LOCAL: no gate
// exchange, no intra-step fence. One s_barrier per step (h handoff only).
// A/B fragment lane layouts are symmetric for 16x16x32 (lane&15 = non-K index,
// lane>>4 = k-group), so Wt build and av reads are identical to R15's.

__global__ __launch_bounds__(256) void lstm_kernel(
    const float* __restrict__ x,      // [B,T,3]
    const float* __restrict__ fc0_w,  // [34,3]
    const float* __restrict__ fc0_b,  // [34]
    const float* __restrict__ w_ih,   // [136,34]
    const float* __restrict__ w_hh,   // [136,34]
    const float* __restrict__ b_ih,   // [136]
    const float* __restrict__ b_hh,   // [136]
    float* __restrict__ out)          // [B,T,34]
{
    __shared__ __align__(16) unsigned short a_lds[2][GB][KP]; // h/x operand, double-buffered

    const int tid  = threadIdx.x;
    const int lane = tid & 63;
    const int wv   = tid >> 6;      // wave id
    const int b    = lane & 15;     // batch (D col / frag non-K index)
    const int kg   = lane >> 4;     // k-group; D-row group

    // cell partition across waves: {9,9,8,8}
    const int nc   = (wv < 2) ? 9 : 8;
    const int base = (wv < 2) ? 9 * wv : 18 + 8 * (wv - 2);

    // ---- one-time: weight A-fragments (3 N-tiles x 3 K-chunks), prescaled ----
    bf16x8 Wt[3][3];
    #pragma unroll
    for (int tau = 0; tau < 3; ++tau) {
        const int rhat = 16 * tau + b;
        const int jl = rhat >> 2, g = rhat & 3;
        const int r = (jl < nc) ? g * Hn + (base + jl) : -1;
        const float s = (g == 2) ? (2.f * L2E) : (-L2E);
        float wcv[3] = {0.f, 0.f, 0.f};
        float bia = 0.f;
        if (r >= 0) {
            float ab = 0.f;
            for (int m = 0; m < Hn; ++m) {
                const float wi = w_ih[r * Hn + m];
                wcv[0] += wi * fc0_w[m * 3 + 0];
                wcv[1] += wi * fc0_w[m * 3 + 1];
                wcv[2] += wi * fc0_w[m * 3 + 2];
                ab     += wi * fc0_b[m];
            }
            wcv[0] *= s; wcv[1] *= s; wcv[2] *= s;
            bia = s * (ab + b_ih[r] + b_hh[r]);
        }
        #pragma unroll
        for (int ks = 0; ks < 3; ++ks) {
            bf16x8 f;
            #pragma unroll
            for (int e = 0; e < 8; ++e) {
                const int k = ks * 32 + kg * 8 + e;
                float val = 0.f;
                if (r >= 0) {
                    if (k < 68)       val = s * w_hh[r * Hn + (k >> 1)];
                    else if (k < 71)  val = wcv[k - 68];
                    else if (k < 74)  val = wcv[k - 71];
                    else if (k < 77)  { const float w = wcv[k - 74]; val = w - bf2f(f2bf(w)); }
                    else if (k == 77) val = bia;                      // bias_h (x1.0 slot)
                    else if (k == 78) val = bia - bf2f(f2bf(bia));    // bias_l
                }
                f[e] = (short)f2bf(val);
            }
            Wt[tau][ks] = f;
        }
    }

    // lane-local cells: jl = 4*tau + kg (tau=0,1 always valid; tau=2 iff 8+kg < nc)
    const bool has2 = (8 + kg < nc);
    float c0 = 0.f, c1 = 0.f, c2 = 0.f;
    float h0 = 0.f, h1 = 0.f, h2 = 0.f;

    // x staging: wave w stages batches 4w..4w+3 (12 lanes x 1 feature)
    const bool xact = (lane < 12);
    const int bx = 4 * wv + lane / 3;
    const int ix = lane - 3 * (lane / 3);

    // ---- zero both A buffers; barrier; bias-1.0 slots + x(0); barrier ----
    for (int i = tid; i < 2 * GB * KP; i += 256) ((unsigned short*)a_lds)[i] = 0;
    block_sync_lds();

    const long long bg = (long long)blockIdx.x * GB;
    const float* xblk = x + bg * (long long)(Tn * 3);
    float* oblk = out + bg * (long long)(Tn * Hn);
    const long long TH = (long long)Tn * Hn;

    if (tid < 32) {   // constant-1.0 slots (bias path), both buffers
        a_lds[tid >> 4][tid & 15][77] = (unsigned short)0x3F80;
        a_lds[tid >> 4][tid & 15][78] = (unsigned short)0x3F80;
    }
    if (xact) {
        const float xr = xblk[bx * (Tn * 3) + ix];
        const unsigned short xh = f2bf(xr);
        a_lds[0][bx][68 + ix] = xh;
        a_lds[0][bx][71 + ix] = f2bf(xr - bf2f(xh));
        a_lds[0][bx][74 + ix] = xh;
    }
    block_sync_lds();

    for (int t = 0; t < Tn; ++t) {
        const int cur = t & 1, nxt = cur ^ 1;

        // ---- top of step: global ops (fire-and-forget; retire under compute) ----
        if (t) {   // store h(t-1) from registers
            const long long tb = (long long)b * TH + (long long)(t - 1) * Hn + base;
            oblk[tb + kg]     = h0;
            oblk[tb + 4 + kg] = h1;
            if (has2) oblk[tb + 8 + kg] = h2;
        }
        float xr = 0.f;
        if (xact && t + 1 < Tn)
            xr = xblk[bx * (Tn * 3) + (t + 1) * 3 + ix];

        // ---- data B-fragments (row = batch = b) ----
        bf16x8 av[3];
        #pragma unroll
        for (int ks = 0; ks < 3; ++ks)
            av[ks] = *(const bf16x8*)(&a_lds[cur][b][ks * 32 + kg * 8]);

        // ---- MFMA (swapped): acc[tau] regs = gates i,f,g,o of cell 4*tau+kg ----
        f32x4 acc[3];
        #pragma unroll
        for (int tau = 0; tau < 3; ++tau) {
            acc[tau] = f32x4{0.f, 0.f, 0.f, 0.f};
            #pragma unroll
            for (int ks = 0; ks < 3; ++ks)
                acc[tau] = __builtin_amdgcn_mfma_f32_16x16x32_bf16(Wt[tau][ks], av[ks], acc[tau], 0, 0, 0);
        }

        // ---- lane-local nonlinearity + cell update (gate = reg index, static) ----
        {
            const float gi = frcp(1.f + fexp2(acc[0][0]));
            const float gf = frcp(1.f + fexp2(acc[0][1]));
            const float gg = fmaf(-2.f, frcp(1.f + fexp2(acc[0][2])), 1.f);
            const float go = frcp(1.f + fexp2(acc[0][3]));
            c0 = gf * c0 + gi * gg;
            h0 = go * fmaf(-2.f, frcp(1.f + fexp2(c0 * (2.f * L2E))), 1.f);
            ((unsigned*)&a_lds[nxt][b][0])[base + kg] = packh(h0);
        }
        {
            const float gi = frcp(1.f + fexp2(acc[1][0]));
            const float gf = frcp(1.f + fexp2(acc[1][1]));
            const float gg = fmaf(-2.f, frcp(1.f + fexp2(acc[1][2])), 1.f);
            const float go = frcp(1.f + fexp2(acc[1][3]));
            c1 = gf * c1 + gi * gg;
            h1 = go * fmaf(-2.f, frcp(1.f + fexp2(c1 * (2.f * L2E))), 1.f);
            ((unsigned*)&a_lds[nxt][b][0])[base + 4 + kg] = packh(h1);
        }
        if (has2) {
            const float gi = frcp(1.f + fexp2(acc[2][0]));
            const float gf = frcp(1.f + fexp2(acc[2][1]));
            const float gg = fmaf(-2.f, frcp(1.f + fexp2(acc[2][2])), 1.f);
            const float go = frcp(1.f + fexp2(acc[2][3]));
            c2 = gf * c2 + gi * gg;
            h2 = go * fmaf(-2.f, frcp(1.f + fexp2(c2 * (2.f * L2E))), 1.f);
            ((unsigned*)&a_lds[nxt][b][0])[base + 8 + kg] = packh(h2);
        }

        // ---- stage x(t+1) into next A buffer ----
        if (xact) {
            const unsigned short xh = f2bf(xr);
            a_lds[nxt][bx][68 + ix] = xh;
            a_lds[nxt][bx][71 + ix] = f2bf(xr - bf2f(xh));
            a_lds[nxt][bx][74 + ix] = xh;
        }

        block_sync_lds();   // the ONE sync/step: h(t) visible to all waves
    }

    // final store: h(Tn-1)
    {
        const long long tb = (long long)b * TH + (long long)(Tn - 1) * Hn + base;
        oblk[tb + kg]     = h0;
        oblk[tb + 4 + kg] = h1;
        if (has2) oblk[tb + 8 + kg] = h2;
    }
}

} // namespace

extern "C" void kernel_launch(void* const* d_in, const int* in_sizes, int n_in,
                              void* d_out, int out_size, void* d_ws, size_t ws_size,
                              hipStream_t stream) {
    const float* x     = (const float*)d_in[0];
    const float* fc0_w = (const float*)d_in[1];
    const float* fc0_b = (const float*)d_in[2];
    const float* w_ih  = (const float*)d_in[3];
    const float* w_hh  = (const float*)d_in[4];
    const float* b_ih  = (const float*)d_in[5];
    const float* b_hh  = (const float*)d_in[6];
    float* out = (float*)d_out;

    lstm_kernel<<<Bn / GB, 256, 0, stream>>>(x, fc0_w, fc0_b, w_ih, w_hh, b_ih, b_hh, out);
}